// Round 2
// baseline (10200.478 us; speedup 1.0000x reference)
//
#include <hip/hip_runtime.h>
#include <hip/hip_bf16.h>
#include <math.h>
#include <stddef.h>

// B=32, P=196, E=256, A=512, M=512, D=512, V=20000, L=52, T=51
// All float inputs are fp32 (per reference). Output buffer fp32.
// Recurrence kept fully fp32; only the hoisted preds GEMM uses bf16 MFMA.

typedef unsigned short ushort_t;
typedef __bf16 bf16x8 __attribute__((ext_vector_type(8)));
typedef float f32x4 __attribute__((ext_vector_type(4)));
typedef unsigned short ushort8 __attribute__((ext_vector_type(8)));

union FragU { ushort8 u; bf16x8 b; };

__device__ __forceinline__ unsigned short f2bu(float f){
  union { float f; unsigned int i; } c; c.f = f;
  unsigned int x = c.i;
  unsigned int r = x + 0x7fffu + ((x >> 16) & 1u);
  return (unsigned short)(r >> 16);
}
__device__ __forceinline__ float bu2f(unsigned short u){
  union { unsigned int i; float f; } c; c.i = ((unsigned int)u) << 16; return c.f;
}
__device__ __forceinline__ float sigm(float x){ return 1.f/(1.f+__expf(-x)); }
__device__ __forceinline__ float ftanh(float x){ float e = __expf(2.f*x); return 1.f - 2.f/(e+1.f); }

// ---- transpose+convert: Wfc fp32 (512 x 20000) -> WfcT bf16 (20000 x 512) -----------------
__global__ __launch_bounds__(256) void k_tcvt(const float* __restrict__ src,
                                              ushort_t* __restrict__ dst, int R, int C){
  __shared__ float tile[32][33];
  int c0 = blockIdx.x*32, r0 = blockIdx.y*32;
  int tx = threadIdx.x & 31, ty = threadIdx.x >> 5;
  #pragma unroll
  for (int i=0;i<4;i++){ int r = ty + i*8; tile[r][tx] = src[(size_t)(r0+r)*C + c0+tx]; }
  __syncthreads();
  #pragma unroll
  for (int i=0;i<4;i++){ int c = ty + i*8; dst[(size_t)(c0+c)*R + r0+tx] = f2bu(tile[tx][c]); }
}

// ---- misc: int outputs, declen, packed step-X bias ----------------------------------------
__global__ __launch_bounds__(256) void k_misc(const int* __restrict__ cap, const int* __restrict__ lens,
                      const float* __restrict__ bdec, const float* __restrict__ bfb,
                      const float* __restrict__ bhh,
                      float* out_cap, float* out_dl, int* declen, float* xbias){
  int tid = blockIdx.x*256 + threadIdx.x;
  if (tid < 32*52) out_cap[tid] = (float)cap[tid];
  if (tid < 32){ int dl = lens[tid]-1; out_dl[tid] = (float)dl; declen[tid] = dl; }
  if (tid < 2816){
    float v = (tid<512) ? bdec[tid] : (tid<768) ? bfb[tid-512] : bhh[tid-768];
    xbias[tid] = v;
  }
}

// ---- init: mean_enc -> h0, c0 (fp32) ------------------------------------------------------
__global__ __launch_bounds__(256) void k_init(const float* __restrict__ enc,
                     const float* __restrict__ Wih_, const float* __restrict__ bih_,
                     const float* __restrict__ Wic_, const float* __restrict__ bic_,
                     float* __restrict__ hbuf, float* __restrict__ cbuf){
  int b = blockIdx.x, tid = threadIdx.x;
  __shared__ float mean_s[256];
  const float* eb = enc + (size_t)b*196*256;
  float s = 0.f;
  for (int p=0;p<196;p++) s += eb[p*256 + tid];
  mean_s[tid] = s * (1.f/196.f);
  __syncthreads();
  float h0=0.f,h1=0.f,c0=0.f,c1=0.f;
  for (int k=0;k<256;k++){
    float m = mean_s[k];
    h0 += m*Wih_[k*512+tid];      h1 += m*Wih_[k*512+tid+256];
    c0 += m*Wic_[k*512+tid];      c1 += m*Wic_[k*512+tid+256];
  }
  hbuf[b*512+tid]     = h0 + bih_[tid];
  hbuf[b*512+tid+256] = h1 + bih_[tid+256];
  cbuf[b*512+tid]     = c0 + bic_[tid];
  cbuf[b*512+tid+256] = c1 + bic_[tid+256];
}

// ---- gather embedding rows (fp32) ---------------------------------------------------------
__global__ __launch_bounds__(256) void k_gather(const int* __restrict__ cap,
                                                const float* __restrict__ emb,
                                                float* __restrict__ erows){
  int row = blockIdx.x; int b = row/51, t = row%51;
  int tok = cap[b*52 + t];
  const float* src = emb + (size_t)tok*512;
  float* dst = erows + (size_t)row*512;
  dst[threadIdx.x]       = src[threadIdx.x];
  dst[threadIdx.x + 256] = src[threadIdx.x + 256];
}

// ---- att1 = enc @ W_enc_att + b (fp32). M=6272,N=512,K=256. 16 rows/block -----------------
__global__ __launch_bounds__(256) void k_att1(const float* __restrict__ enc,
                      const float* __restrict__ Wenc, const float* __restrict__ benc,
                      float* __restrict__ att1){
  __shared__ float e_s[16][256];
  int r0 = blockIdx.x*16, tid = threadIdx.x;
  for (int i=tid; i<16*256; i+=256){ int r=i>>8, k=i&255; e_s[r][k] = enc[(size_t)(r0+r)*256 + k]; }
  __syncthreads();
  float a0[16], a1[16];
  #pragma unroll
  for (int r=0;r<16;r++){ a0[r]=0.f; a1[r]=0.f; }
  for (int k=0;k<256;k++){
    float w0 = Wenc[k*512 + tid], w1 = Wenc[k*512 + tid + 256];
    #pragma unroll
    for (int r=0;r<16;r++){ a0[r] += e_s[r][k]*w0; a1[r] += e_s[r][k]*w1; }
  }
  float b0 = benc[tid], b1 = benc[tid+256];
  for (int r=0;r<16;r++){
    att1[(size_t)(r0+r)*512 + tid]       = a0[r] + b0;
    att1[(size_t)(r0+r)*512 + tid + 256] = a1[r] + b1;
  }
}

// ---- eih = erows @ W_ih[0:512,:] + b_ih (fp32). M=1632,N=2048,K=512. 16 rows/block --------
__global__ __launch_bounds__(256) void k_eih(const float* __restrict__ erows,
                     const float* __restrict__ Wih, const float* __restrict__ bih,
                     float* __restrict__ eih, int Mrows){
  __shared__ float e_s[16][512];
  int r0 = blockIdx.y*16, col = blockIdx.x*256 + threadIdx.x, tid = threadIdx.x;
  for (int i=tid; i<16*512; i+=256){
    int r=i>>9, k=i&511;
    e_s[r][k] = (r0+r < Mrows) ? erows[(size_t)(r0+r)*512 + k] : 0.f;
  }
  __syncthreads();
  float acc[16];
  #pragma unroll
  for (int r=0;r<16;r++) acc[r]=0.f;
  for (int k=0;k<512;k++){
    float w = Wih[(size_t)k*2048 + col];
    #pragma unroll
    for (int r=0;r<16;r++) acc[r] += e_s[r][k]*w;
  }
  float bv = bih[col];
  for (int r=0;r<16;r++) if (r0+r < Mrows) eih[(size_t)(r0+r)*2048 + col] = acc[r] + bv;
}

// ---- step X: XO[b][0:2816] = h @ [W_dec|W_fbeta|W_hh] + bias (fp32) -----------------------
// grid (11, 4): x = 256-col group, y = 8-batch group
__global__ __launch_bounds__(256)
void k_stepX(const float* __restrict__ hbuf,
             const float* __restrict__ Wdec, const float* __restrict__ Wfb,
             const float* __restrict__ Whh,
             const float* __restrict__ xbias, float* __restrict__ XO)
{
  __shared__ float h_s[8][512];
  int tid = threadIdx.x, cg = blockIdx.x;
  const float* W; int ldw, lcol;
  if (cg < 2)      { W = Wdec; ldw = 512;  lcol = cg*256 + tid; }
  else if (cg == 2){ W = Wfb;  ldw = 256;  lcol = tid; }
  else             { W = Whh;  ldw = 2048; lcol = (cg-3)*256 + tid; }
  int ocol = cg*256 + tid;
  int b0 = blockIdx.y*8;
  for (int i=tid; i<8*512; i+=256){ int bb=i>>9, k=i&511; h_s[bb][k] = hbuf[(b0+bb)*512 + k]; }
  __syncthreads();
  float acc[8];
  #pragma unroll
  for (int bb=0;bb<8;bb++) acc[bb]=0.f;
  for (int k=0;k<512;k++){
    float w = W[(size_t)k*ldw + lcol];
    #pragma unroll
    for (int bb=0;bb<8;bb++) acc[bb] += w*h_s[bb][k];
  }
  float bv = xbias[ocol];
  #pragma unroll
  for (int bb=0;bb<8;bb++) XO[(size_t)(b0+bb)*2816 + ocol] = acc[bb] + bv;
}

// ---- step Y1: att scores, softmax, awe, gate -> xawe, alphas (fp32) -----------------------
__global__ __launch_bounds__(256)
void k_stepY1(const float* __restrict__ att1, const float* __restrict__ XO,
              const float* __restrict__ wfull, const float* __restrict__ enc,
              const int* __restrict__ declen, int t,
              float* __restrict__ out_alphas, float* __restrict__ xawe)
{
  int b = blockIdx.x, tid = threadIdx.x;
  __shared__ float att2_s[512];
  __shared__ float wf_s[512];
  __shared__ float alpha_s[196];
  __shared__ float red_s[40];
  const float* xo = XO + (size_t)b*2816;
  for (int i=tid;i<512;i+=256){ att2_s[i]=xo[i]; wf_s[i]=wfull[i]; }
  __syncthreads();
  float av = -1e30f;
  if (tid < 196){
    const float* arow = att1 + ((size_t)b*196 + tid)*512;
    float s = 0.f;
    for (int k=0;k<512;k+=4){
      float4 v = *(const float4*)(arow + k);
      s += fmaxf(v.x + att2_s[k+0], 0.f)*wf_s[k+0];
      s += fmaxf(v.y + att2_s[k+1], 0.f)*wf_s[k+1];
      s += fmaxf(v.z + att2_s[k+2], 0.f)*wf_s[k+2];
      s += fmaxf(v.w + att2_s[k+3], 0.f)*wf_s[k+3];
    }
    av = s;
  }
  float m = av;
  #pragma unroll
  for (int off=32;off>0;off>>=1) m = fmaxf(m, __shfl_down(m, off, 64));
  if ((tid&63)==0) red_s[tid>>6] = m;
  __syncthreads();
  if (tid==0) red_s[16] = fmaxf(fmaxf(red_s[0],red_s[1]), fmaxf(red_s[2],red_s[3]));
  __syncthreads();
  float gmax = red_s[16];
  float ev = (tid<196) ? __expf(av - gmax) : 0.f;
  float ssum = ev;
  #pragma unroll
  for (int off=32;off>0;off>>=1) ssum += __shfl_down(ssum, off, 64);
  if ((tid&63)==0) red_s[20+(tid>>6)] = ssum;
  __syncthreads();
  if (tid==0) red_s[17] = red_s[20]+red_s[21]+red_s[22]+red_s[23];
  __syncthreads();
  float inv = 1.f/red_s[17];
  int mask = (t < declen[b]) ? 1 : 0;
  if (tid<196){
    float al = ev*inv;
    alpha_s[tid] = al;
    out_alphas[((size_t)b*51 + t)*196 + tid] = mask ? al : 0.f;
  }
  __syncthreads();
  const float* eb = enc + (size_t)b*196*256;
  float aw = 0.f;
  for (int p=0;p<196;p++) aw += alpha_s[p]*eb[p*256 + tid];
  float gate = sigm(xo[512+tid]);
  xawe[b*256+tid] = gate*aw;
}

// ---- step Y2: gates = xawe@W_ih[512:768,:] + XO_hh + eih; LSTM update (fp32) --------------
// grid 32: block = (bg = blk>>3 over 4 groups of 8 batches, dg = blk&7 over 8 groups of 64 d)
__global__ __launch_bounds__(256)
void k_stepY2(const float* __restrict__ Wih, const float* __restrict__ xawe,
              const float* __restrict__ XO, const float* __restrict__ eih, int t,
              const int* __restrict__ declen,
              float* __restrict__ hbuf, float* __restrict__ cbuf, ushort_t* __restrict__ hallb)
{
  __shared__ float x_s[8][256];
  __shared__ float g_s[4][8][64];
  int blk = blockIdx.x, tid = threadIdx.x;
  int bg = blk>>3, dg = blk&7;
  int g = tid>>6, dd = tid&63;
  int col = g*512 + dg*64 + dd;
  const float* WihB = Wih + (size_t)512*2048;
  for (int i=tid; i<8*256; i+=256){ int bb=i>>8, k=i&255; x_s[bb][k] = xawe[(bg*8+bb)*256 + k]; }
  __syncthreads();
  float acc[8];
  #pragma unroll
  for (int bb=0;bb<8;bb++) acc[bb]=0.f;
  for (int k=0;k<256;k++){
    float w = WihB[(size_t)k*2048 + col];
    #pragma unroll
    for (int bb=0;bb<8;bb++) acc[bb] += w*x_s[bb][k];
  }
  #pragma unroll
  for (int bb=0;bb<8;bb++){
    int b = bg*8+bb;
    g_s[g][bb][dd] = acc[bb] + XO[(size_t)b*2816 + 768 + col] + eih[((size_t)b*51 + t)*2048 + col];
  }
  __syncthreads();
  #pragma unroll
  for (int r=0;r<2;r++){
    int pi = tid + 256*r;
    int bb = pi>>6, d2 = pi&63;
    int b = bg*8+bb, d = dg*64+d2;
    float iv = sigm(g_s[0][bb][d2]);
    float fv = sigm(g_s[1][bb][d2]);
    float gv = ftanh(g_s[2][bb][d2]);
    float ov = sigm(g_s[3][bb][d2]);
    float cold = cbuf[b*512 + d];
    float cnew = fv*cold + iv*gv;
    float hnew = ov*ftanh(cnew);
    hallb[((size_t)b*51 + t)*512 + d] = f2bu(hnew);
    if (t < declen[b]){ cbuf[b*512 + d] = cnew; hbuf[b*512 + d] = hnew; }
  }
}

// ---- bf16 MFMA GEMM for preds: C = A(MxK) * Bt(NxK)^T + bias, masked rows zeroed ----------
#define LDT 40
__global__ __launch_bounds__(256)
void k_gemm(const ushort_t* __restrict__ Ag, int lda,
            const ushort_t* __restrict__ Bg, int ldb,
            int Mrows, int Ncols, int K,
            const float* __restrict__ bias,
            float* __restrict__ outF, int ldo,
            const int* __restrict__ declen)
{
  __shared__ ushort_t As[128*LDT];
  __shared__ ushort_t Bs[128*LDT];
  int m0 = blockIdx.y*128, n0 = blockIdx.x*128;
  int tid = threadIdx.x;
  int wave = tid>>6, lane = tid&63;
  int wm = wave>>1, wn = wave&1;
  int q = lane>>4, r = lane&15;
  f32x4 acc[4][4];
  f32x4 zero4 = {0.f,0.f,0.f,0.f};
  #pragma unroll
  for(int i=0;i<4;i++){ acc[i][0]=zero4; acc[i][1]=zero4; acc[i][2]=zero4; acc[i][3]=zero4; }

  for (int k0=0; k0<K; k0+=32){
    __syncthreads();
    #pragma unroll
    for (int c=tid; c<512; c+=256){
      int row = c>>2, ko = (c&3)*8;
      ushort8 v = {0,0,0,0,0,0,0,0};
      if (m0+row < Mrows) v = *(const ushort8*)(Ag + (size_t)(m0+row)*lda + k0 + ko);
      *(ushort8*)(As + row*LDT + ko) = v;
      ushort8 wv = {0,0,0,0,0,0,0,0};
      if (n0+row < Ncols) wv = *(const ushort8*)(Bg + (size_t)(n0+row)*ldb + k0 + ko);
      *(ushort8*)(Bs + row*LDT + ko) = wv;
    }
    __syncthreads();
    FragU a[4], bb[4];
    #pragma unroll
    for(int i=0;i<4;i++){
      a[i].u  = *(const ushort8*)(As + (64*wm + 16*i + r)*LDT + 8*q);
      bb[i].u = *(const ushort8*)(Bs + (64*wn + 16*i + r)*LDT + 8*q);
    }
    #pragma unroll
    for(int i=0;i<4;i++)
      #pragma unroll
      for(int j=0;j<4;j++)
        acc[i][j] = __builtin_amdgcn_mfma_f32_16x16x32_bf16(a[i].b, bb[j].b, acc[i][j], 0,0,0);
  }
  #pragma unroll
  for(int i=0;i<4;i++){
    int rowbase = m0 + 64*wm + 16*i + q*4;
    #pragma unroll
    for(int j=0;j<4;j++){
      int col = n0 + 64*wn + 16*j + r;
      if (col >= Ncols) continue;
      float bv = bias ? bias[col] : 0.f;
      #pragma unroll
      for(int rr=0;rr<4;rr++){
        int row = rowbase + rr;
        if (row >= Mrows) continue;
        float v = acc[i][j][rr] + bv;
        if (declen){ int tt = row % 51; int b = row / 51; if (tt >= declen[b]) v = 0.f; }
        outF[(size_t)row*ldo + col] = v;
      }
    }
  }
}

// -------------------------------------------------------------------------------------------
extern "C" void kernel_launch(void* const* d_in, const int* in_sizes, int n_in,
                              void* d_out, int out_size, void* d_ws, size_t ws_size,
                              hipStream_t stream)
{
  const float* enc   = (const float*)d_in[0];
  const int*   cap   = (const int*)d_in[1];
  const int*   lens  = (const int*)d_in[2];
  const float* Wenc  = (const float*)d_in[3];
  const float* benc  = (const float*)d_in[4];
  const float* Wdec  = (const float*)d_in[5];
  const float* bdec  = (const float*)d_in[6];
  const float* Wfull = (const float*)d_in[7];
  // d_in[8] = b_full_att: softmax-invariant, skipped
  const float* emb   = (const float*)d_in[9];
  const float* Wih   = (const float*)d_in[10];
  const float* bih   = (const float*)d_in[11];
  const float* Whh   = (const float*)d_in[12];
  const float* bhh   = (const float*)d_in[13];
  const float* Winh  = (const float*)d_in[14];
  const float* binh  = (const float*)d_in[15];
  const float* Winc  = (const float*)d_in[16];
  const float* binc  = (const float*)d_in[17];
  const float* Wfb   = (const float*)d_in[18];
  const float* bfb   = (const float*)d_in[19];
  const float* Wfc   = (const float*)d_in[20];
  const float* bfc   = (const float*)d_in[21];
  float* out = (float*)d_out;

  char* w = (char*)d_ws;
  size_t off = 0;
  auto alloc = [&](size_t bytes)->char*{ char* p = w + off; off += (bytes + 255) & ~(size_t)255; return p; };
  ushort_t* WfcT  = (ushort_t*)alloc(20000ull*512*2);  // bf16, transposed
  float*    att1  = (float*)alloc(6272ull*512*4);
  float*    erows = (float*)alloc(1632ull*512*4);
  float*    eih   = (float*)alloc(1632ull*2048*4);
  ushort_t* hallb = (ushort_t*)alloc(1632ull*512*2);   // bf16 h_new history (A for preds GEMM)
  float*    XO    = (float*)alloc(32ull*2816*4);
  float*    xawe  = (float*)alloc(32ull*256*4);
  float*    hbuf  = (float*)alloc(32ull*512*4);
  float*    cbuf  = (float*)alloc(32ull*512*4);
  float*    xbias = (float*)alloc(2816*4);
  int*      declen= (int*)alloc(32*4);

  float* out_preds = out;                        // 32*51*20000
  float* out_cap   = out + 32640000ull;          // 32*52
  float* out_dl    = out_cap + 1664;             // 32
  float* out_alph  = out_dl + 32;                // 32*51*196

  // preamble
  k_tcvt<<<dim3(625,16),256,0,stream>>>(Wfc, WfcT, 512, 20000);
  k_misc<<<11,256,0,stream>>>(cap, lens, bdec, bfb, bhh, out_cap, out_dl, declen, xbias);
  k_init<<<32,256,0,stream>>>(enc, Winh, binh, Winc, binc, hbuf, cbuf);
  k_gather<<<1632,256,0,stream>>>(cap, emb, erows);
  k_att1<<<392,256,0,stream>>>(enc, Wenc, benc, att1);
  k_eih<<<dim3(8,102),256,0,stream>>>(erows, Wih, bih, eih, 1632);

  for (int t=0; t<51; t++){
    k_stepX <<<dim3(11,4),256,0,stream>>>(hbuf, Wdec, Wfb, Whh, xbias, XO);
    k_stepY1<<<32,256,0,stream>>>(att1, XO, Wfull, enc, declen, t, out_alph, xawe);
    k_stepY2<<<32,256,0,stream>>>(Wih, xawe, XO, eih, t, declen, hbuf, cbuf, hallb);
  }

  // preds = hall @ W_fc + b_fc (bf16 MFMA), masked rows zeroed. M=1632, N=20000, K=512
  k_gemm<<<dim3(157,13),256,0,stream>>>(hallb, 512, WfcT, 512, 1632, 20000, 512, bfc, out_preds, 20000, declen);
}

// Round 3
// 2812.482 us; speedup vs baseline: 3.6269x; 3.6269x over previous
//
#include <hip/hip_runtime.h>
#include <hip/hip_bf16.h>
#include <math.h>
#include <stddef.h>

// B=32, P=196, E=256, A=512, M=512, D=512, V=20000, L=52, T=51
// fp32 inputs/outputs. Recurrence state h carried in bf16 (margin: round-2 absmax
// 0.00195 vs threshold 399), c carried fp32. All per-step matmuls are MFMA skinny
// GEMMs (M=32) with LDS-staged bf16 weights.

typedef unsigned short ushort_t;
typedef __bf16 bf16x8 __attribute__((ext_vector_type(8)));
typedef float f32x4 __attribute__((ext_vector_type(4)));
typedef unsigned short ushort8 __attribute__((ext_vector_type(8)));
typedef unsigned short ushort4v __attribute__((ext_vector_type(4)));

union FragU { ushort8 u; bf16x8 b; };

__device__ __forceinline__ unsigned short f2bu(float f){
  union { float f; unsigned int i; } c; c.f = f;
  unsigned int x = c.i;
  unsigned int r = x + 0x7fffu + ((x >> 16) & 1u);
  return (unsigned short)(r >> 16);
}
__device__ __forceinline__ float bu2f(unsigned short u){
  union { unsigned int i; float f; } c; c.i = ((unsigned int)u) << 16; return c.f;
}
__device__ __forceinline__ float sigm(float x){ return 1.f/(1.f+__expf(-x)); }
__device__ __forceinline__ float ftanh(float x){ float e = __expf(2.f*x); return 1.f - 2.f/(e+1.f); }

// ---- transpose + fp32->bf16 convert: dst[(c0+c)*ldd + r] = src[r*C + c] ------------------
__global__ __launch_bounds__(256) void k_cvtT(const float* __restrict__ src, int C,
                                              ushort_t* __restrict__ dst, int ldd){
  __shared__ float tile[32][33];
  int c0 = blockIdx.x*32, r0 = blockIdx.y*32;
  int tx = threadIdx.x & 31, ty = threadIdx.x >> 5;
  #pragma unroll
  for (int i=0;i<4;i++){ int r = ty + i*8; tile[r][tx] = src[(size_t)(r0+r)*C + c0+tx]; }
  __syncthreads();
  #pragma unroll
  for (int i=0;i<4;i++){ int c = ty + i*8; dst[(size_t)(c0+c)*ldd + r0+tx] = f2bu(tile[tx][c]); }
}

// ---- elementwise fp32 -> bf16 (vectorized by 4) -------------------------------------------
__global__ __launch_bounds__(256) void k_cvt4(const float* __restrict__ src,
                                              ushort_t* __restrict__ dst, int n4){
  int i = blockIdx.x*256 + threadIdx.x;
  if (i < n4){
    float4 v = ((const float4*)src)[i];
    ushort4v o; o.x=f2bu(v.x); o.y=f2bu(v.y); o.z=f2bu(v.z); o.w=f2bu(v.w);
    ((ushort4v*)dst)[i] = o;
  }
}

// ---- misc: int outputs, declen, packed/reordered biases -----------------------------------
__global__ __launch_bounds__(256) void k_misc(const int* __restrict__ cap, const int* __restrict__ lens,
                      const float* __restrict__ bdec, const float* __restrict__ bfb,
                      const float* __restrict__ bih, const float* __restrict__ bhh,
                      float* out_cap, float* out_dl, int* declen,
                      float* xbias, float* bihR, float* bhhR){
  int tid = blockIdx.x*256 + threadIdx.x;
  if (tid < 32*52) out_cap[tid] = (float)cap[tid];
  if (tid < 32){ int dl = lens[tid]-1; out_dl[tid] = (float)dl; declen[tid] = dl; }
  if (tid < 768) xbias[tid] = (tid<512) ? bdec[tid] : bfb[tid-512];
  if (tid < 2048){
    int c = (tid&3)*512 + (tid>>2);   // reordered col r=d*4+g <- original c=g*512+d
    bihR[tid] = bih[c];
    bhhR[tid] = bhh[c];
  }
}

// ---- init: mean_enc -> h0 (bf16), c0 (fp32) -----------------------------------------------
__global__ __launch_bounds__(256) void k_init(const float* __restrict__ enc,
                     const float* __restrict__ Wih_, const float* __restrict__ bih_,
                     const float* __restrict__ Wic_, const float* __restrict__ bic_,
                     ushort_t* __restrict__ hnewb, float* __restrict__ cbuf){
  int b = blockIdx.x, tid = threadIdx.x;
  __shared__ float mean_s[256];
  const float* eb = enc + (size_t)b*196*256;
  float s = 0.f;
  for (int p=0;p<196;p++) s += eb[p*256 + tid];
  mean_s[tid] = s * (1.f/196.f);
  __syncthreads();
  float h0=0.f,h1=0.f,c0=0.f,c1=0.f;
  for (int k=0;k<256;k++){
    float m = mean_s[k];
    h0 += m*Wih_[k*512+tid];      h1 += m*Wih_[k*512+tid+256];
    c0 += m*Wic_[k*512+tid];      c1 += m*Wic_[k*512+tid+256];
  }
  hnewb[b*512+tid]     = f2bu(h0 + bih_[tid]);
  hnewb[b*512+tid+256] = f2bu(h1 + bih_[tid+256]);
  cbuf[b*512+tid]      = c0 + bic_[tid];
  cbuf[b*512+tid+256]  = c1 + bic_[tid+256];
}

// ---- gather embedding rows -> bf16 --------------------------------------------------------
__global__ __launch_bounds__(256) void k_gather(const int* __restrict__ cap,
                                                const float* __restrict__ emb,
                                                ushort_t* __restrict__ erowsb){
  int row = blockIdx.x; int b = row/51, t = row%51;
  int tok = cap[b*52 + t];
  const float* src = emb + (size_t)tok*512;
  ushort_t* dst = erowsb + (size_t)row*512;
  dst[threadIdx.x]       = f2bu(src[threadIdx.x]);
  dst[threadIdx.x + 256] = f2bu(src[threadIdx.x + 256]);
}

// ---- generic bf16 MFMA GEMM: C = A(MxK) @ Bt(NxK)^T + bias --------------------------------
// outF (fp32, optional declen row-mask) or outH (bf16). permB: B row = (n&3)*512+(n>>2).
#define LDT 40
__global__ __launch_bounds__(256)
void k_gemm(const ushort_t* __restrict__ Ag, int lda,
            const ushort_t* __restrict__ Bg, int ldb,
            int Mrows, int Ncols, int K, int permB,
            const float* __restrict__ bias,
            float* __restrict__ outF, ushort_t* __restrict__ outH, int ldo,
            const int* __restrict__ declen)
{
  __shared__ ushort_t As[128*LDT];
  __shared__ ushort_t Bs[128*LDT];
  int m0 = blockIdx.y*128, n0 = blockIdx.x*128;
  int tid = threadIdx.x;
  int wave = tid>>6, lane = tid&63;
  int wm = wave>>1, wn = wave&1;
  int q = lane>>4, r = lane&15;
  f32x4 acc[4][4];
  f32x4 zero4 = {0.f,0.f,0.f,0.f};
  #pragma unroll
  for(int i=0;i<4;i++){ acc[i][0]=zero4; acc[i][1]=zero4; acc[i][2]=zero4; acc[i][3]=zero4; }

  for (int k0=0; k0<K; k0+=32){
    __syncthreads();
    #pragma unroll
    for (int c=tid; c<512; c+=256){
      int row = c>>2, ko = (c&3)*8;
      ushort8 v = {0,0,0,0,0,0,0,0};
      if (m0+row < Mrows) v = *(const ushort8*)(Ag + (size_t)(m0+row)*lda + k0 + ko);
      *(ushort8*)(As + row*LDT + ko) = v;
      ushort8 wv = {0,0,0,0,0,0,0,0};
      int g = n0+row;
      if (g < Ncols){
        int srow = permB ? ((g&3)*512 + (g>>2)) : g;
        wv = *(const ushort8*)(Bg + (size_t)srow*ldb + k0 + ko);
      }
      *(ushort8*)(Bs + row*LDT + ko) = wv;
    }
    __syncthreads();
    FragU a[4], bb[4];
    #pragma unroll
    for(int i=0;i<4;i++){
      a[i].u  = *(const ushort8*)(As + (64*wm + 16*i + r)*LDT + 8*q);
      bb[i].u = *(const ushort8*)(Bs + (64*wn + 16*i + r)*LDT + 8*q);
    }
    #pragma unroll
    for(int i=0;i<4;i++)
      #pragma unroll
      for(int j=0;j<4;j++)
        acc[i][j] = __builtin_amdgcn_mfma_f32_16x16x32_bf16(a[i].b, bb[j].b, acc[i][j], 0,0,0);
  }
  #pragma unroll
  for(int i=0;i<4;i++){
    int rowbase = m0 + 64*wm + 16*i + q*4;
    #pragma unroll
    for(int j=0;j<4;j++){
      int col = n0 + 64*wn + 16*j + r;
      if (col >= Ncols) continue;
      float bv = bias ? bias[col] : 0.f;
      #pragma unroll
      for(int rr=0;rr<4;rr++){
        int row = rowbase + rr;
        if (row >= Mrows) continue;
        float v = acc[i][j][rr] + bv;
        if (declen){ int tt = row % 51; int b = row / 51; if (tt >= declen[b]) v = 0.f; }
        if (outF) outF[(size_t)row*ldo + col] = v;
        else      outH[(size_t)row*ldo + col] = f2bu(v);
      }
    }
  }
}

// ---- skinny MFMA GEMM: C[32][N] = A[32][K] @ Bt(NxK)^T, 128 cols/block, 4 waves -----------
// mode 0: XO[row*ldo+col] = acc + bias[col]
// mode 1: fused LSTM epilogue (cols reordered r=d*4+g via permB on B rows)
__global__ __launch_bounds__(256)
void k_skinny(const ushort_t* __restrict__ A, int lda,
              const ushort_t* __restrict__ B, int ldb, int K, int permB,
              int mode, const float* __restrict__ bias, float* __restrict__ XO, int ldo,
              const ushort_t* __restrict__ eihR, int t, const int* __restrict__ declen,
              float* __restrict__ cbuf, ushort_t* __restrict__ hnewb,
              ushort_t* __restrict__ hallb)
{
  __shared__ ushort_t As[32*LDT];
  __shared__ ushort_t Bs[128*LDT];
  __shared__ float gl[32][128];
  int n0 = blockIdx.x*128;
  int tid = threadIdx.x, wave = tid>>6, lane = tid&63;
  int q = lane>>4, r = lane&15;
  f32x4 acc[2][2];
  f32x4 zero4 = {0.f,0.f,0.f,0.f};
  acc[0][0]=zero4; acc[0][1]=zero4; acc[1][0]=zero4; acc[1][1]=zero4;

  for (int k0=0; k0<K; k0+=32){
    __syncthreads();
    #pragma unroll
    for (int s=tid; s<640; s+=256){
      if (s < 128){
        int row=s>>2, ko=(s&3)*8;
        *(ushort8*)(As + row*LDT + ko) = *(const ushort8*)(A + (size_t)row*lda + k0 + ko);
      } else {
        int s2=s-128; int row=s2>>2, ko=(s2&3)*8;
        int g = n0+row;
        int srow = permB ? ((g&3)*512 + (g>>2)) : g;
        *(ushort8*)(Bs + row*LDT + ko) = *(const ushort8*)(B + (size_t)srow*ldb + k0 + ko);
      }
    }
    __syncthreads();
    FragU a0,a1,b0,b1;
    a0.u = *(const ushort8*)(As + (r)*LDT + 8*q);
    a1.u = *(const ushort8*)(As + (16+r)*LDT + 8*q);
    b0.u = *(const ushort8*)(Bs + (32*wave + r)*LDT + 8*q);
    b1.u = *(const ushort8*)(Bs + (32*wave + 16 + r)*LDT + 8*q);
    acc[0][0] = __builtin_amdgcn_mfma_f32_16x16x32_bf16(a0.b, b0.b, acc[0][0], 0,0,0);
    acc[0][1] = __builtin_amdgcn_mfma_f32_16x16x32_bf16(a0.b, b1.b, acc[0][1], 0,0,0);
    acc[1][0] = __builtin_amdgcn_mfma_f32_16x16x32_bf16(a1.b, b0.b, acc[1][0], 0,0,0);
    acc[1][1] = __builtin_amdgcn_mfma_f32_16x16x32_bf16(a1.b, b1.b, acc[1][1], 0,0,0);
  }

  if (mode == 0){
    #pragma unroll
    for (int i=0;i<2;i++){
      int rowbase = 16*i + 4*q;
      #pragma unroll
      for (int jj=0;jj<2;jj++){
        int col = n0 + 32*wave + 16*jj + r;
        float bv = bias[col];
        #pragma unroll
        for (int rr=0;rr<4;rr++)
          XO[(size_t)(rowbase+rr)*ldo + col] = acc[i][jj][rr] + bv;
      }
    }
  } else {
    #pragma unroll
    for (int i=0;i<2;i++){
      int rowbase = 16*i + 4*q;
      #pragma unroll
      for (int jj=0;jj<2;jj++){
        int cloc = 32*wave + 16*jj + r;
        float bv = bias[n0 + cloc];
        #pragma unroll
        for (int rr=0;rr<4;rr++) gl[rowbase+rr][cloc] = acc[i][jj][rr] + bv;
      }
    }
    __syncthreads();
    #pragma unroll
    for (int it=0; it<4; it++){
      int idx = it*256 + tid;
      int b = idx>>5, dl = idx&31;
      int d = (n0>>2) + dl;
      float4 g4 = *(const float4*)&gl[b][dl*4];
      ushort4v e4 = *(const ushort4v*)(eihR + ((size_t)(b*51+t))*2048 + n0 + dl*4);
      float gi = g4.x + bu2f(e4.x);
      float gf = g4.y + bu2f(e4.y);
      float gg = g4.z + bu2f(e4.z);
      float go = g4.w + bu2f(e4.w);
      float cold = cbuf[b*512 + d];
      float cnew = sigm(gf)*cold + sigm(gi)*ftanh(gg);
      float hnew = sigm(go)*ftanh(cnew);
      hallb[((size_t)(b*51+t))*512 + d] = f2bu(hnew);
      if (t < declen[b]){ cbuf[b*512+d] = cnew; hnewb[b*512+d] = f2bu(hnew); }
    }
  }
}

// ---- step Y1: scores, softmax, awe, gate -> alphas, xawe (into Ahc); copy h into Ahc ------
__global__ __launch_bounds__(256)
void k_stepY1(const ushort_t* __restrict__ att1b, const float* __restrict__ XO,
              const float* __restrict__ wfull, const ushort_t* __restrict__ encb,
              const ushort_t* __restrict__ hnewb,
              const int* __restrict__ declen, int t,
              float* __restrict__ out_alphas, ushort_t* __restrict__ Ahc)
{
  int b = blockIdx.x, tid = threadIdx.x;
  __shared__ float att2_s[512];
  __shared__ float wf_s[512];
  __shared__ float alpha_s[196];
  __shared__ float red_s[40];
  const float* xo = XO + (size_t)b*768;
  for (int i=tid;i<512;i+=256){ att2_s[i]=xo[i]; wf_s[i]=wfull[i]; }
  // refresh Ahc h-columns from hnewb (result of previous step's LSTM)
  Ahc[(size_t)b*768 + tid]       = hnewb[b*512 + tid];
  Ahc[(size_t)b*768 + tid + 256] = hnewb[b*512 + tid + 256];
  __syncthreads();
  float av = -1e30f;
  if (tid < 196){
    const ushort_t* arow = att1b + ((size_t)b*196 + tid)*512;
    float s = 0.f;
    for (int k=0;k<512;k+=8){
      ushort8 v = *(const ushort8*)(arow + k);
      #pragma unroll
      for (int u=0;u<8;u++) s += fmaxf(bu2f(v[u]) + att2_s[k+u], 0.f)*wf_s[k+u];
    }
    av = s;
  }
  float m = av;
  #pragma unroll
  for (int off=32;off>0;off>>=1) m = fmaxf(m, __shfl_down(m, off, 64));
  if ((tid&63)==0) red_s[tid>>6] = m;
  __syncthreads();
  if (tid==0) red_s[16] = fmaxf(fmaxf(red_s[0],red_s[1]), fmaxf(red_s[2],red_s[3]));
  __syncthreads();
  float gmax = red_s[16];
  float ev = (tid<196) ? __expf(av - gmax) : 0.f;
  float ssum = ev;
  #pragma unroll
  for (int off=32;off>0;off>>=1) ssum += __shfl_down(ssum, off, 64);
  if ((tid&63)==0) red_s[20+(tid>>6)] = ssum;
  __syncthreads();
  if (tid==0) red_s[17] = red_s[20]+red_s[21]+red_s[22]+red_s[23];
  __syncthreads();
  float inv = 1.f/red_s[17];
  int mask = (t < declen[b]) ? 1 : 0;
  if (tid<196){
    float al = ev*inv;
    alpha_s[tid] = al;
    out_alphas[((size_t)b*51 + t)*196 + tid] = mask ? al : 0.f;
  }
  __syncthreads();
  const ushort_t* eb = encb + (size_t)b*196*256;
  float aw = 0.f;
  for (int p=0;p<196;p++) aw += alpha_s[p]*bu2f(eb[p*256 + tid]);
  float gate = sigm(xo[512+tid]);
  Ahc[(size_t)b*768 + 512 + tid] = f2bu(gate*aw);
}

// -------------------------------------------------------------------------------------------
extern "C" void kernel_launch(void* const* d_in, const int* in_sizes, int n_in,
                              void* d_out, int out_size, void* d_ws, size_t ws_size,
                              hipStream_t stream)
{
  const float* enc   = (const float*)d_in[0];
  const int*   cap   = (const int*)d_in[1];
  const int*   lens  = (const int*)d_in[2];
  const float* Wenc  = (const float*)d_in[3];
  const float* benc  = (const float*)d_in[4];
  const float* Wdec  = (const float*)d_in[5];
  const float* bdec  = (const float*)d_in[6];
  const float* Wfull = (const float*)d_in[7];
  // d_in[8] = b_full_att: softmax-invariant, skipped
  const float* emb   = (const float*)d_in[9];
  const float* Wih   = (const float*)d_in[10];
  const float* bih   = (const float*)d_in[11];
  const float* Whh   = (const float*)d_in[12];
  const float* bhh   = (const float*)d_in[13];
  const float* Winh  = (const float*)d_in[14];
  const float* binh  = (const float*)d_in[15];
  const float* Winc  = (const float*)d_in[16];
  const float* binc  = (const float*)d_in[17];
  const float* Wfb   = (const float*)d_in[18];
  const float* bfb   = (const float*)d_in[19];
  const float* Wfc   = (const float*)d_in[20];
  const float* bfc   = (const float*)d_in[21];
  float* out = (float*)d_out;

  char* w = (char*)d_ws;
  size_t off = 0;
  auto alloc = [&](size_t bytes)->char*{ char* p = w + off; off += (bytes + 255) & ~(size_t)255; return p; };
  ushort_t* WfcT    = (ushort_t*)alloc(20000ull*512*2);  // [20000][512]
  ushort_t* WHC     = (ushort_t*)alloc(2048ull*768*2);   // [2048][768] = [Whh^T | WihBot^T]
  ushort_t* WihTopT = (ushort_t*)alloc(2048ull*512*2);   // [2048][512]
  ushort_t* XWT768  = (ushort_t*)alloc(768ull*512*2);    // [768][512] = [Wdec^T ; Wfb^T]
  ushort_t* WencT   = (ushort_t*)alloc(512ull*256*2);    // [512][256]
  ushort_t* encb    = (ushort_t*)alloc(32ull*196*256*2);
  ushort_t* erowsb  = (ushort_t*)alloc(1632ull*512*2);
  ushort_t* att1b   = (ushort_t*)alloc(6272ull*512*2);
  ushort_t* eihR    = (ushort_t*)alloc(1632ull*2048*2);  // reordered cols r=d*4+g, incl. b_ih
  ushort_t* hallb   = (ushort_t*)alloc(1632ull*512*2);
  ushort_t* hnewb   = (ushort_t*)alloc(32ull*512*2);
  ushort_t* Ahc     = (ushort_t*)alloc(32ull*768*2);     // [h | xawe] bf16
  float*    XO      = (float*)alloc(32ull*768*4);
  float*    cbuf    = (float*)alloc(32ull*512*4);
  float*    xbias   = (float*)alloc(768*4);
  float*    bihR    = (float*)alloc(2048*4);
  float*    bhhR    = (float*)alloc(2048*4);
  int*      declen  = (int*)alloc(32*4);

  float* out_preds = out;                        // 32*51*20000
  float* out_cap   = out + 32640000ull;          // 32*52
  float* out_dl    = out_cap + 1664;             // 32
  float* out_alph  = out_dl + 32;                // 32*51*196

  // ---- preamble: weight conversions/transposes (one-time) ----
  k_cvtT<<<dim3(625,16),256,0,stream>>>(Wfc, 20000, WfcT, 512);
  k_cvtT<<<dim3(64,16), 256,0,stream>>>(Whh, 2048, WHC, 768);                    // k 0..511
  k_cvtT<<<dim3(64,8),  256,0,stream>>>(Wih + 512ull*2048, 2048, WHC + 512, 768);// k 512..767
  k_cvtT<<<dim3(64,16), 256,0,stream>>>(Wih, 2048, WihTopT, 512);
  k_cvtT<<<dim3(16,16), 256,0,stream>>>(Wdec, 512, XWT768, 512);
  k_cvtT<<<dim3(8,16),  256,0,stream>>>(Wfb, 256, XWT768 + 512ull*512, 512);
  k_cvtT<<<dim3(16,8),  256,0,stream>>>(Wenc, 512, WencT, 256);
  k_cvt4<<<1568,256,0,stream>>>(enc, encb, 401408);
  k_misc<<<8,256,0,stream>>>(cap, lens, bdec, bfb, bih, bhh, out_cap, out_dl, declen, xbias, bihR, bhhR);
  k_init<<<32,256,0,stream>>>(enc, Winh, binh, Winc, binc, hnewb, cbuf);
  k_gather<<<1632,256,0,stream>>>(cap, emb, erowsb);
  // att1b = encb @ WencT^T + benc  (6272 x 512, K=256) -> bf16
  k_gemm<<<dim3(4,49),256,0,stream>>>(encb, 256, WencT, 256, 6272, 512, 256, 0, benc, nullptr, att1b, 512, nullptr);
  // eihR = erowsb @ WihTopT^T (permuted cols) + bihR  (1632 x 2048, K=512) -> bf16
  k_gemm<<<dim3(16,13),256,0,stream>>>(erowsb, 512, WihTopT, 512, 1632, 2048, 512, 1, bihR, nullptr, eihR, 2048, nullptr);

  // ---- 51 sequential steps: 3 launches each ----
  for (int t=0; t<51; t++){
    // XO[32][768] = h @ [Wdec|Wfb] + [bdec|bfb]
    k_skinny<<<6,256,0,stream>>>(hnewb, 512, XWT768, 512, 512, 0,
                                 0, xbias, XO, 768, nullptr, 0, nullptr, nullptr, nullptr, nullptr);
    k_stepY1<<<32,256,0,stream>>>(att1b, XO, Wfull, encb, hnewb, declen, t, out_alph, Ahc);
    // gates = [h|xawe] @ WHC^T(reordered) + bhhR + eihR ; fused LSTM
    k_skinny<<<16,256,0,stream>>>(Ahc, 768, WHC, 768, 768, 1,
                                 1, bhhR, nullptr, 0, eihR, t, declen, cbuf, hnewb, hallb);
  }

  // preds = hallb @ WfcT^T + bfc (masked rows zeroed). M=1632, N=20000, K=512
  k_gemm<<<dim3(157,13),256,0,stream>>>(hallb, 512, WfcT, 512, 1632, 20000, 512, 0, bfc, out_preds, nullptr, 20000, declen);
}

// Round 4
// 2409.673 us; speedup vs baseline: 4.2331x; 1.1672x over previous
//
#include <hip/hip_runtime.h>
#include <hip/hip_bf16.h>
#include <math.h>
#include <stddef.h>

// B=32, P=196, E=256, A=512, M=512, D=512, V=20000, L=52, T=51
// fp32 in/out. Step loop fused into ONE persistent kernel (88 blocks) with a
// device-scope grid barrier; per-step matmuls are 32-col MFMA tiles.

typedef unsigned short ushort_t;
typedef __bf16 bf16x8 __attribute__((ext_vector_type(8)));
typedef float f32x4 __attribute__((ext_vector_type(4)));
typedef unsigned short ushort8 __attribute__((ext_vector_type(8)));
typedef unsigned short ushort4v __attribute__((ext_vector_type(4)));

union FragU { ushort8 u; bf16x8 b; };

__device__ __forceinline__ unsigned short f2bu(float f){
  union { float f; unsigned int i; } c; c.f = f;
  unsigned int x = c.i;
  unsigned int r = x + 0x7fffu + ((x >> 16) & 1u);
  return (unsigned short)(r >> 16);
}
__device__ __forceinline__ float bu2f(unsigned short u){
  union { unsigned int i; float f; } c; c.i = ((unsigned int)u) << 16; return c.f;
}
__device__ __forceinline__ float sigm(float x){ return 1.f/(1.f+__expf(-x)); }
__device__ __forceinline__ float ftanh(float x){ float e = __expf(2.f*x); return 1.f - 2.f/(e+1.f); }

// ---- device-scope grid barrier (count + generation) ---------------------------------------
__device__ __forceinline__ void gridbar(int* cnt, int* gen, int nb){
  __syncthreads();
  if (threadIdx.x == 0){
    __threadfence();  // flush this XCD's L2 (release)
    int g = __hip_atomic_load(gen, __ATOMIC_RELAXED, __HIP_MEMORY_SCOPE_AGENT);
    if (__hip_atomic_fetch_add(cnt, 1, __ATOMIC_ACQ_REL, __HIP_MEMORY_SCOPE_AGENT) == nb-1){
      __hip_atomic_store(cnt, 0, __ATOMIC_RELAXED, __HIP_MEMORY_SCOPE_AGENT);
      __hip_atomic_fetch_add(gen, 1, __ATOMIC_ACQ_REL, __HIP_MEMORY_SCOPE_AGENT);
    } else {
      while (__hip_atomic_load(gen, __ATOMIC_RELAXED, __HIP_MEMORY_SCOPE_AGENT) == g)
        __builtin_amdgcn_s_sleep(2);
    }
    __threadfence();  // invalidate stale lines (acquire)
  }
  __syncthreads();
}

// ---- transpose + fp32->bf16; optional dest-row permute r=d*4+g (for 2048-col gate mats) ---
__global__ __launch_bounds__(256) void k_cvtT(const float* __restrict__ src, int C,
                                              ushort_t* __restrict__ dst, int ldd, int perm){
  __shared__ float tile[32][33];
  int c0 = blockIdx.x*32, r0 = blockIdx.y*32;
  int tx = threadIdx.x & 31, ty = threadIdx.x >> 5;
  #pragma unroll
  for (int i=0;i<4;i++){ int r = ty + i*8; tile[r][tx] = src[(size_t)(r0+r)*C + c0+tx]; }
  __syncthreads();
  #pragma unroll
  for (int i=0;i<4;i++){
    int c = ty + i*8;
    int row = c0 + c;
    if (perm) row = ((row & 511) << 2) | (row >> 9);   // g*512+d -> d*4+g
    dst[(size_t)row*ldd + r0+tx] = f2bu(tile[tx][c]);
  }
}

// ---- elementwise fp32 -> bf16 -------------------------------------------------------------
__global__ __launch_bounds__(256) void k_cvt4(const float* __restrict__ src,
                                              ushort_t* __restrict__ dst, int n4){
  int i = blockIdx.x*256 + threadIdx.x;
  if (i < n4){
    float4 v = ((const float4*)src)[i];
    ushort4v o; o.x=f2bu(v.x); o.y=f2bu(v.y); o.z=f2bu(v.z); o.w=f2bu(v.w);
    ((ushort4v*)dst)[i] = o;
  }
}

// ---- misc: int outputs, declen, biases, zero barrier --------------------------------------
__global__ __launch_bounds__(256) void k_misc(const int* __restrict__ cap, const int* __restrict__ lens,
                      const float* __restrict__ bdec, const float* __restrict__ bfb,
                      const float* __restrict__ bih, const float* __restrict__ bhh,
                      float* out_cap, float* out_dl, int* declen,
                      float* xbias, float* bihR, float* bhhR, int* barcnt, int* bargen){
  int tid = blockIdx.x*256 + threadIdx.x;
  if (tid == 0){ *barcnt = 0; *bargen = 0; }
  if (tid < 32*52) out_cap[tid] = (float)cap[tid];
  if (tid < 32){ int dl = lens[tid]-1; out_dl[tid] = (float)dl; declen[tid] = dl; }
  if (tid < 768) xbias[tid] = (tid<512) ? bdec[tid] : bfb[tid-512];
  if (tid < 2048){
    int c = (tid&3)*512 + (tid>>2);   // reordered col r=d*4+g <- original c=g*512+d
    bihR[tid] = bih[c];
    bhhR[tid] = bhh[c];
  }
}

// ---- init: mean_enc -> h0 (bf16), c0 (fp32) -----------------------------------------------
__global__ __launch_bounds__(256) void k_init(const float* __restrict__ enc,
                     const float* __restrict__ Wih_, const float* __restrict__ bih_,
                     const float* __restrict__ Wic_, const float* __restrict__ bic_,
                     ushort_t* __restrict__ hnewb, float* __restrict__ cbuf){
  int b = blockIdx.x, tid = threadIdx.x;
  __shared__ float mean_s[256];
  const float* eb = enc + (size_t)b*196*256;
  float s = 0.f;
  for (int p=0;p<196;p++) s += eb[p*256 + tid];
  mean_s[tid] = s * (1.f/196.f);
  __syncthreads();
  float h0=0.f,h1=0.f,c0=0.f,c1=0.f;
  for (int k=0;k<256;k++){
    float m = mean_s[k];
    h0 += m*Wih_[k*512+tid];      h1 += m*Wih_[k*512+tid+256];
    c0 += m*Wic_[k*512+tid];      c1 += m*Wic_[k*512+tid+256];
  }
  hnewb[b*512+tid]     = f2bu(h0 + bih_[tid]);
  hnewb[b*512+tid+256] = f2bu(h1 + bih_[tid+256]);
  cbuf[b*512+tid]      = c0 + bic_[tid];
  cbuf[b*512+tid+256]  = c1 + bic_[tid+256];
}

// ---- gather embedding rows -> bf16 --------------------------------------------------------
__global__ __launch_bounds__(256) void k_gather(const int* __restrict__ cap,
                                                const float* __restrict__ emb,
                                                ushort_t* __restrict__ erowsb){
  int row = blockIdx.x; int b = row/51, t = row%51;
  int tok = cap[b*52 + t];
  const float* src = emb + (size_t)tok*512;
  ushort_t* dst = erowsb + (size_t)row*512;
  dst[threadIdx.x]       = f2bu(src[threadIdx.x]);
  dst[threadIdx.x + 256] = f2bu(src[threadIdx.x + 256]);
}

// ---- generic bf16 MFMA GEMM (128x128 tile); optional XCD-aware flat mapping ---------------
#define LDT 40
__global__ __launch_bounds__(256)
void k_gemm(const ushort_t* __restrict__ Ag, int lda,
            const ushort_t* __restrict__ Bg, int ldb,
            int Mrows, int Ncols, int K,
            const float* __restrict__ bias,
            float* __restrict__ outF, ushort_t* __restrict__ outH, int ldo,
            const int* __restrict__ declen,
            int Mtiles, int Ntiles, int xcdswz)
{
  __shared__ ushort_t As[128*LDT];
  __shared__ ushort_t Bs[128*LDT];
  int m0, n0;
  if (xcdswz){
    int l = blockIdx.x; int xcd = l & 7; int i = l >> 3;
    int mt = i % Mtiles; int ns = i / Mtiles;
    int nt = ns*8 + xcd;
    if (nt >= Ntiles) return;
    m0 = mt*128; n0 = nt*128;
  } else {
    m0 = blockIdx.y*128; n0 = blockIdx.x*128;
  }
  int tid = threadIdx.x;
  int wave = tid>>6, lane = tid&63;
  int wm = wave>>1, wn = wave&1;
  int q = lane>>4, r = lane&15;
  f32x4 acc[4][4];
  f32x4 zero4 = {0.f,0.f,0.f,0.f};
  #pragma unroll
  for(int i=0;i<4;i++){ acc[i][0]=zero4; acc[i][1]=zero4; acc[i][2]=zero4; acc[i][3]=zero4; }

  for (int k0=0; k0<K; k0+=32){
    __syncthreads();
    #pragma unroll
    for (int c=tid; c<512; c+=256){
      int row = c>>2, ko = (c&3)*8;
      ushort8 v = {0,0,0,0,0,0,0,0};
      if (m0+row < Mrows) v = *(const ushort8*)(Ag + (size_t)(m0+row)*lda + k0 + ko);
      *(ushort8*)(As + row*LDT + ko) = v;
      ushort8 wv = {0,0,0,0,0,0,0,0};
      if (n0+row < Ncols) wv = *(const ushort8*)(Bg + (size_t)(n0+row)*ldb + k0 + ko);
      *(ushort8*)(Bs + row*LDT + ko) = wv;
    }
    __syncthreads();
    FragU a[4], bb[4];
    #pragma unroll
    for(int i=0;i<4;i++){
      a[i].u  = *(const ushort8*)(As + (64*wm + 16*i + r)*LDT + 8*q);
      bb[i].u = *(const ushort8*)(Bs + (64*wn + 16*i + r)*LDT + 8*q);
    }
    #pragma unroll
    for(int i=0;i<4;i++)
      #pragma unroll
      for(int j=0;j<4;j++)
        acc[i][j] = __builtin_amdgcn_mfma_f32_16x16x32_bf16(a[i].b, bb[j].b, acc[i][j], 0,0,0);
  }
  #pragma unroll
  for(int i=0;i<4;i++){
    int rowbase = m0 + 64*wm + 16*i + q*4;
    #pragma unroll
    for(int j=0;j<4;j++){
      int col = n0 + 64*wn + 16*j + r;
      if (col >= Ncols) continue;
      float bv = bias ? bias[col] : 0.f;
      #pragma unroll
      for(int rr=0;rr<4;rr++){
        int row = rowbase + rr;
        if (row >= Mrows) continue;
        float v = acc[i][j][rr] + bv;
        if (declen){ int tt = row % 51; int b = row / 51; if (tt >= declen[b]) v = 0.f; }
        if (outF) outF[(size_t)row*ldo + col] = v;
        else      outH[(size_t)row*ldo + col] = f2bu(v);
      }
    }
  }
}

// ---- 32x32 MFMA tile: C(32 x 32cols) = A(32xK) @ Brows(32xK)^T, K templated ---------------
template<int K>
__device__ __forceinline__ f32x4 tile32(const ushort_t* __restrict__ Ag, int lda,
                                        const ushort_t* __restrict__ Bg, int ldb,
                                        ushort_t* As, ushort_t* Bs){
  const int KW = K/8, LDS = K+8;
  int tid = threadIdx.x, wave = tid>>6, lane = tid&63;
  int q = lane>>4, r = lane&15;
  int wm = (wave>>1)*16, wn = (wave&1)*16;
  for (int i=tid; i<32*KW; i+=256){
    int row = i/KW, ko = (i%KW)*8;
    *(ushort8*)(As + row*LDS + ko) = *(const ushort8*)(Ag + (size_t)row*lda + ko);
    *(ushort8*)(Bs + row*LDS + ko) = *(const ushort8*)(Bg + (size_t)row*ldb + ko);
  }
  __syncthreads();
  f32x4 acc = {0.f,0.f,0.f,0.f};
  #pragma unroll
  for (int kc=0; kc<K; kc+=32){
    FragU a, b;
    a.u = *(const ushort8*)(As + (wm + r)*LDS + kc + 8*q);
    b.u = *(const ushort8*)(Bs + (wn + r)*LDS + kc + 8*q);
    acc = __builtin_amdgcn_mfma_f32_16x16x32_bf16(a.b, b.b, acc, 0,0,0);
  }
  return acc;
}

// ---- persistent fused step loop: 88 blocks ------------------------------------------------
#define NB 88
__global__ __launch_bounds__(256)
void k_steps(const ushort_t* __restrict__ XWT768, const ushort_t* __restrict__ WHCp,
             const float* __restrict__ xbias, const float* __restrict__ bhhR,
             const ushort_t* __restrict__ att1b, const float* __restrict__ wfull,
             const ushort_t* __restrict__ encb, const ushort_t* __restrict__ eihR,
             const int* __restrict__ declen,
             ushort_t* __restrict__ hnewb, float* __restrict__ cbuf,
             float* __restrict__ XO, float* __restrict__ gatesH,
             ushort_t* __restrict__ xaweb, ushort_t* __restrict__ hallb,
             float* __restrict__ out_alph, int* barcnt, int* bargen)
{
  int blk = blockIdx.x, tid = threadIdx.x;
  int wave = tid>>6, lane = tid&63;
  int q = lane>>4, r = lane&15;
  int wm = (wave>>1)*16, wn = (wave&1)*16;
  __shared__ ushort_t As[32*520];
  __shared__ ushort_t Bs[32*520];
  __shared__ float gl[32][32];

  for (int t=0; t<51; t++){
    // ---------- phase A: XO = h@[Wdec|Wfb]+b (24 blks); gatesH = h@Whh^T(reord)+bhh (64) ---
    if (blk < 24){
      int n0 = blk*32;
      f32x4 acc = tile32<512>(hnewb, 512, XWT768 + (size_t)n0*512, 512, As, Bs);
      int col = n0 + wn + r;
      float bv = xbias[col];
      #pragma unroll
      for (int rr=0;rr<4;rr++) XO[(size_t)(wm + 4*q + rr)*768 + col] = acc[rr] + bv;
    } else {
      int n0 = (blk-24)*32;
      f32x4 acc = tile32<512>(hnewb, 512, WHCp + (size_t)n0*768, 768, As, Bs);
      int col = n0 + wn + r;
      float bv = bhhR[col];
      #pragma unroll
      for (int rr=0;rr<4;rr++) gatesH[(size_t)(wm + 4*q + rr)*2048 + col] = acc[rr] + bv;
    }
    gridbar(barcnt, bargen, NB);

    // ---------- phase B: attention + softmax + awe + gate (32 blocks, one per batch) -------
    if (blk < 32){
      int b = blk;
      float* att2_s  = (float*)As;           // 512
      float* wf_s    = att2_s + 512;         // 512
      float* alpha_s = wf_s + 512;           // 196
      float* red_s   = alpha_s + 200;        // 40
      const float* xo = XO + (size_t)b*768;
      for (int i=tid;i<512;i+=256){ att2_s[i]=xo[i]; wf_s[i]=wfull[i]; }
      __syncthreads();
      float av = -1e30f;
      if (tid < 196){
        const ushort_t* arow = att1b + ((size_t)b*196 + tid)*512;
        float s = 0.f;
        for (int k=0;k<512;k+=8){
          ushort8 v = *(const ushort8*)(arow + k);
          #pragma unroll
          for (int u=0;u<8;u++) s += fmaxf(bu2f(v[u]) + att2_s[k+u], 0.f)*wf_s[k+u];
        }
        av = s;
      }
      float m = av;
      #pragma unroll
      for (int off=32;off>0;off>>=1) m = fmaxf(m, __shfl_down(m, off, 64));
      if ((tid&63)==0) red_s[tid>>6] = m;
      __syncthreads();
      if (tid==0) red_s[16] = fmaxf(fmaxf(red_s[0],red_s[1]), fmaxf(red_s[2],red_s[3]));
      __syncthreads();
      float gmax = red_s[16];
      float ev = (tid<196) ? __expf(av - gmax) : 0.f;
      float ssum = ev;
      #pragma unroll
      for (int off=32;off>0;off>>=1) ssum += __shfl_down(ssum, off, 64);
      if ((tid&63)==0) red_s[20+(tid>>6)] = ssum;
      __syncthreads();
      if (tid==0) red_s[17] = red_s[20]+red_s[21]+red_s[22]+red_s[23];
      __syncthreads();
      float inv = 1.f/red_s[17];
      int mask = (t < declen[b]) ? 1 : 0;
      if (tid<196){
        float al = ev*inv;
        alpha_s[tid] = al;
        out_alph[((size_t)b*51 + t)*196 + tid] = mask ? al : 0.f;
      }
      __syncthreads();
      const ushort_t* eb = encb + (size_t)b*196*256;
      float aw = 0.f;
      for (int p=0;p<196;p++) aw += alpha_s[p]*bu2f(eb[p*256 + tid]);
      float gate = sigm(xo[512+tid]);
      xaweb[b*256 + tid] = f2bu(gate*aw);
    }
    gridbar(barcnt, bargen, NB);

    // ---------- phase C: gates = gatesH + xawe@WihBot^T(reord) + eihR; LSTM (64 blocks) ----
    if (blk < 64){
      int n0 = blk*32;
      f32x4 acc = tile32<256>(xaweb, 256, WHCp + (size_t)n0*768 + 512, 768, As, Bs);
      int col = n0 + wn + r;
      #pragma unroll
      for (int rr=0;rr<4;rr++){
        int row = wm + 4*q + rr;
        gl[row][wn + r] = acc[rr] + gatesH[(size_t)row*2048 + col]
                        + bu2f(eihR[((size_t)row*51 + t)*2048 + col]);
      }
      __syncthreads();
      int b = tid>>3, dd = tid&7;
      int d = (n0>>2) + dd;
      float gi = gl[b][dd*4+0], gf = gl[b][dd*4+1], gg = gl[b][dd*4+2], go = gl[b][dd*4+3];
      float cold = cbuf[b*512 + d];
      float cnew = sigm(gf)*cold + sigm(gi)*ftanh(gg);
      float hnew = sigm(go)*ftanh(cnew);
      hallb[((size_t)b*51 + t)*512 + d] = f2bu(hnew);
      if (t < declen[b]){ cbuf[b*512 + d] = cnew; hnewb[b*512 + d] = f2bu(hnew); }
    }
    gridbar(barcnt, bargen, NB);
  }
}

// -------------------------------------------------------------------------------------------
extern "C" void kernel_launch(void* const* d_in, const int* in_sizes, int n_in,
                              void* d_out, int out_size, void* d_ws, size_t ws_size,
                              hipStream_t stream)
{
  const float* enc   = (const float*)d_in[0];
  const int*   cap   = (const int*)d_in[1];
  const int*   lens  = (const int*)d_in[2];
  const float* Wenc  = (const float*)d_in[3];
  const float* benc  = (const float*)d_in[4];
  const float* Wdec  = (const float*)d_in[5];
  const float* bdec  = (const float*)d_in[6];
  const float* Wfull = (const float*)d_in[7];
  // d_in[8] = b_full_att: softmax-invariant, skipped
  const float* emb   = (const float*)d_in[9];
  const float* Wih   = (const float*)d_in[10];
  const float* bih   = (const float*)d_in[11];
  const float* Whh   = (const float*)d_in[12];
  const float* bhh   = (const float*)d_in[13];
  const float* Winh  = (const float*)d_in[14];
  const float* binh  = (const float*)d_in[15];
  const float* Winc  = (const float*)d_in[16];
  const float* binc  = (const float*)d_in[17];
  const float* Wfb   = (const float*)d_in[18];
  const float* bfb   = (const float*)d_in[19];
  const float* Wfc   = (const float*)d_in[20];
  const float* bfc   = (const float*)d_in[21];
  float* out = (float*)d_out;

  char* w = (char*)d_ws;
  size_t off = 0;
  auto alloc = [&](size_t bytes)->char*{ char* p = w + off; off += (bytes + 255) & ~(size_t)255; return p; };
  ushort_t* WfcT    = (ushort_t*)alloc(20000ull*512*2);  // [20000][512]
  ushort_t* WHCp    = (ushort_t*)alloc(2048ull*768*2);   // rows r=d*4+g; k: [Whh^T | WihBot^T]
  ushort_t* WihTopTp= (ushort_t*)alloc(2048ull*512*2);   // rows r=d*4+g
  ushort_t* XWT768  = (ushort_t*)alloc(768ull*512*2);    // [Wdec^T ; Wfb^T]
  ushort_t* WencT   = (ushort_t*)alloc(512ull*256*2);
  ushort_t* encb    = (ushort_t*)alloc(32ull*196*256*2);
  ushort_t* erowsb  = (ushort_t*)alloc(1632ull*512*2);
  ushort_t* att1b   = (ushort_t*)alloc(6272ull*512*2);
  ushort_t* eihR    = (ushort_t*)alloc(1632ull*2048*2);  // cols r=d*4+g, incl. b_ih
  ushort_t* hallb   = (ushort_t*)alloc(1632ull*512*2);
  ushort_t* hnewb   = (ushort_t*)alloc(32ull*512*2);
  ushort_t* xaweb   = (ushort_t*)alloc(32ull*256*2);
  float*    XO      = (float*)alloc(32ull*768*4);
  float*    gatesH  = (float*)alloc(32ull*2048*4);
  float*    cbuf    = (float*)alloc(32ull*512*4);
  float*    xbias   = (float*)alloc(768*4);
  float*    bihR    = (float*)alloc(2048*4);
  float*    bhhR    = (float*)alloc(2048*4);
  int*      declen  = (int*)alloc(32*4);
  int*      barcnt  = (int*)alloc(256);
  int*      bargen  = (int*)alloc(256);

  float* out_preds = out;                        // 32*51*20000
  float* out_cap   = out + 32640000ull;          // 32*52
  float* out_dl    = out_cap + 1664;             // 32
  float* out_alph  = out_dl + 32;                // 32*51*196

  // ---- preamble ----
  k_cvtT<<<dim3(625,16),256,0,stream>>>(Wfc, 20000, WfcT, 512, 0);
  k_cvtT<<<dim3(64,16), 256,0,stream>>>(Whh, 2048, WHCp, 768, 1);                     // k 0..511
  k_cvtT<<<dim3(64,8),  256,0,stream>>>(Wih + 512ull*2048, 2048, WHCp + 512, 768, 1); // k 512..767
  k_cvtT<<<dim3(64,16), 256,0,stream>>>(Wih, 2048, WihTopTp, 512, 1);
  k_cvtT<<<dim3(16,16), 256,0,stream>>>(Wdec, 512, XWT768, 512, 0);
  k_cvtT<<<dim3(8,16),  256,0,stream>>>(Wfb, 256, XWT768 + 512ull*512, 512, 0);
  k_cvtT<<<dim3(16,8),  256,0,stream>>>(Wenc, 512, WencT, 256, 0);
  k_cvt4<<<1568,256,0,stream>>>(enc, encb, 401408);
  k_misc<<<8,256,0,stream>>>(cap, lens, bdec, bfb, bih, bhh, out_cap, out_dl, declen,
                             xbias, bihR, bhhR, barcnt, bargen);
  k_init<<<32,256,0,stream>>>(enc, Winh, binh, Winc, binc, hnewb, cbuf);
  k_gather<<<1632,256,0,stream>>>(cap, emb, erowsb);
  // att1b = encb @ WencT^T + benc  (6272 x 512, K=256) -> bf16
  k_gemm<<<dim3(4,49),256,0,stream>>>(encb, 256, WencT, 256, 6272, 512, 256,
                                      benc, nullptr, att1b, 512, nullptr, 0,0,0);
  // eihR = erowsb @ WihTopTp^T + bihR  (1632 x 2048(reord), K=512) -> bf16
  k_gemm<<<dim3(16,13),256,0,stream>>>(erowsb, 512, WihTopTp, 512, 1632, 2048, 512,
                                       bihR, nullptr, eihR, 2048, nullptr, 0,0,0);

  // ---- fused 51-step recurrence: ONE launch ----
  k_steps<<<NB,256,0,stream>>>(XWT768, WHCp, xbias, bhhR, att1b, Wfull, encb, eihR, declen,
                               hnewb, cbuf, XO, gatesH, xaweb, hallb, out_alph, barcnt, bargen);

  // ---- preds = hallb @ WfcT^T + bfc (masked). M=1632, N=20000, K=512; XCD-aware mapping ---
  k_gemm<<<2080,256,0,stream>>>(hallb, 512, WfcT, 512, 1632, 20000, 512,
                                bfc, out_preds, nullptr, 20000, declen, 13, 157, 1);
}